// Round 5
// baseline (4137.090 us; speedup 1.0000x reference)
//
#include <hip/hip_runtime.h>
#include <hip/hip_bf16.h>

// ---------------------------------------------------------------------------
// NeuralODE: 64 Tsit5 steps, f = 128->512->512->128 MLP (tanh, tanh, linear)
// Fused persistent kernel: 256 wgs x 512 threads, each wg owns 32 batch rows.
// Transposed GEMMs (out^T = W^T @ in^T) with mfma_f32_32x32x16_bf16.
// V6: continuous async weight pipeline (V5 + T3/T4).
//   V5 diagnosis: HBM ~0 (weights L2-resident), eval = 22.3k cyc vs 13.7k cyc
//   L2-stream floor; gap = per-layer load restart latency + __syncthreads'
//   vmcnt(0) drain killing prefetch.
//   - Each wave stages its A-tiles into a private 4KB LDS double-buffer via
//     global_load_lds (width 16), issued 2 pairs (2KB each) ahead.
//   - Consumption = fixed 48-pair cycle per eval (L1:8, L2:32, L3:8) that
//     wraps into the next eval (weights don't depend on activations).
//   - All barriers are raw s_barrier + lgkmcnt(0) (NEVER vmcnt(0)) so the
//     DMA pipeline survives phase boundaries.
//   - Per step: lgkm(0); ISSUE pair s+2; vmcnt(2); ds_read pair s+1 + next
//     B-frag (register double-buffer); MFMA pair s.  In flight: 8 waves x
//     4KB = 32KB/CU ~= 56 B/cyc x L2 latency -> saturates the L2 stream.
//   - Integrator k-state stays in LDS (V5's de-spill win, FETCH ~0).
// fp32 state/accumulators; bf16 only on GEMM operands.
// ---------------------------------------------------------------------------

#define NSTEPS 64

typedef __attribute__((ext_vector_type(8))) short short8;
typedef __attribute__((ext_vector_type(16))) float f32x16;

// LDS layout (bytes)
static constexpr int OFF_YT   = 0;                 // 8 KB: ytmp (B-frags, 8 blocks)
static constexpr int OFF_H    = 8192;              // 32 KB: H (layer1 out, then layer2 out in-place)
static constexpr int KO_S     = 129;               // k row stride (floats), pad vs 128
static constexpr int K_BYTES  = 32 * KO_S * 4;     // 16512 B per k buffer
static constexpr int OFF_K0   = 8192 + 32768;      // five k buffers (k6 reuses K0)
static constexpr int OFF_BIAS = OFF_K0 + 5 * K_BYTES;            // 4608 B
static constexpr int OFF_ST   = OFF_BIAS + 1152 * 4;             // 128128: staging
static constexpr int SMEM_BYTES = OFF_ST + 8 * 4096;             // 160896 B

// weight block indices (1 block = 64 uint4 = 1 KB)
#define W1B(mt, kc) ((mt) * 8 + (kc))
#define W2B(mt, kc) (128 + (mt) * 32 + (kc))
#define W3B(mt, kc) (640 + (mt) * 32 + (kc))

// waits / barrier (compiler-fenced on both sides; no vmcnt drain!)
#define VMCNT2() asm volatile("s_waitcnt vmcnt(2)" ::: "memory")
#define VMCNT0() asm volatile("s_waitcnt vmcnt(0)" ::: "memory")
#define LGKM0()  asm volatile("s_waitcnt lgkmcnt(0)" ::: "memory")
#define HBAR()   do { LGKM0(); __builtin_amdgcn_s_barrier(); \
                      asm volatile("" ::: "memory"); } while (0)

// Tsit5 coefficients
#define C_A21 0.161f
#define C_A31 (-0.008480655492356989f)
#define C_A32 0.335480655492357f
#define C_A41 2.8971530571054935f
#define C_A42 (-6.359448489975075f)
#define C_A43 4.3622954328695815f
#define C_A51 5.325864828439257f
#define C_A52 (-11.748883564062828f)
#define C_A53 7.4955393428898365f
#define C_A54 (-0.09249506636175525f)
#define C_A61 5.86145544294642f
#define C_A62 (-12.92096931784711f)
#define C_A63 8.159367898576159f
#define C_A64 (-0.071584973281401f)
#define C_A65 (-0.028269050394068383f)
#define C_B1 0.09646076681806523f
#define C_B2 0.01f
#define C_B3 0.4798896504144996f
#define C_B4 1.379008574103742f
#define C_B5 (-3.290069515436081f)
#define C_B6 2.324710524099774f

__device__ __forceinline__ float fast_tanh(float x) {
    float e = __builtin_amdgcn_exp2f(x * 2.88539008177792681472f);
    return 1.0f - 2.0f * __builtin_amdgcn_rcpf(e + 1.0f);
}

__device__ __forceinline__ unsigned int pack2(float a, float b) {
    unsigned short lo = __builtin_bit_cast(unsigned short, __float2bfloat16(a));
    unsigned short hi = __builtin_bit_cast(unsigned short, __float2bfloat16(b));
    return ((unsigned int)hi << 16) | (unsigned int)lo;
}

#define MFMA(a, b, c) __builtin_amdgcn_mfma_f32_32x32x16_bf16((a), (b), (c), 0, 0, 0)

// async 16B/lane DMA: lane l of the wave lands at ldst + l*16 (linear layout)
__device__ __forceinline__ void dma16(const uint4* __restrict__ g, char* s_) {
    __builtin_amdgcn_global_load_lds(
        (const __attribute__((address_space(1))) void*)g,
        (__attribute__((address_space(3))) void*)s_, 16, 0, 0);
}

// Write one C tile (f32x16) as tanh(C+bias) into B-frag-layout bf16 LDS buffer.
__device__ __forceinline__ void store_h(char* smem, int dstOff, const f32x16& acc,
                                        int mt, int q, int lm, const float* bias) {
#pragma unroll
    for (int gblk = 0; gblk < 4; ++gblk) {
        const int r0   = gblk * 4;
        const int row0 = 8 * (r0 >> 2) + 4 * q;
        const int m0   = mt * 32 + row0;
        float v0 = fast_tanh(acc[r0]     + bias[m0]);
        float v1 = fast_tanh(acc[r0 + 1] + bias[m0 + 1]);
        float v2 = fast_tanh(acc[r0 + 2] + bias[m0 + 2]);
        float v3 = fast_tanh(acc[r0 + 3] + bias[m0 + 3]);
        uint2 dw;
        dw.x = pack2(v0, v1);
        dw.y = pack2(v2, v3);
        const int b  = 2 * mt + (r0 >> 3);
        const int s  = lm + 32 * ((r0 >> 2) & 1);
        const int sp = (s + b) & 63;
        *(uint2*)(smem + dstOff + (b << 10) + (sp << 4) + (q << 3)) = dw;
    }
}

// ytmp (B of layer 1): thread t owns (batch row t>>4, d cols 8*(t&15)..+8)
__device__ __forceinline__ void write_ytmp(char* smem, int tid, const float* v) {
    const int b  = (tid & 15) >> 1;
    const int s  = (tid >> 4) + 32 * (tid & 1);
    const int sp = (s + b) & 63;
    uint4 pk;
    pk.x = pack2(v[0], v[1]);
    pk.y = pack2(v[2], v[3]);
    pk.z = pack2(v[4], v[5]);
    pk.w = pack2(v[6], v[7]);
    *(uint4*)(smem + OFF_YT + (b << 10) + (sp << 4)) = pk;
}

// read this thread's 8-element slice of a k buffer
__device__ __forceinline__ void read_k(const char* smem, int koOff, int tid, float* k) {
    const float* ko = (const float*)(smem + koOff);
    const int kb = (tid >> 4) * KO_S + (tid & 15) * 8;
#pragma unroll
    for (int i = 0; i < 8; ++i) k[i] = ko[kb + i];
}

#define LD_YT(kc) (*(const short8*)(smem + OFF_YT + ((kc) << 10) + (((l + (kc)) & 63) << 4)))
#define LD_H(kc)  (*(const short8*)(smem + OFF_H  + ((kc) << 10) + (((l + (kc)) & 63) << 4)))

// One full MLP evaluation: sYtmp -> k buffer at koOff (f32 [32][KO_S]).
// Pipeline invariant at entry AND exit: the next 2 pairs (4 KB) of this
// wave's A-tile sequence are issued (pair g landed, pair g+1 maybe in flight).
__device__ __forceinline__ void mlp_eval(char* smem, const uint4* __restrict__ wp,
                                         int tid, int koOff) {
    const int l   = tid & 63;
    const int w   = tid >> 6;
    const int q   = l >> 5;
    const int lm  = l & 31;
    const int mt0 = 2 * w, mt1 = mt0 + 1;
    const int mt3 = w & 3, kc03 = (w >> 2) * 16;
    const float* sb = (const float*)(smem + OFF_BIAS);
    char* stw = smem + OFF_ST + (w << 12);       // this wave's 4 KB staging

    HBAR();   // sYtmp visible (also bias on first call); DMA stays in flight

    uint4 a0c, a1c, a0n, a1n;
    short8 bc, bn, b0c, b1c, b0n, b1n;

    // ---- Layer 1: H = tanh(W1t @ Yt + b1), steps s=0..7 (pairs 0..7) ----
    {
        f32x16 acc0, acc1;
#pragma unroll
        for (int i = 0; i < 16; ++i) { acc0[i] = 0.f; acc1[i] = 0.f; }
        VMCNT2();                                 // pair 0 landed
        a0c = *(const uint4*)(stw + (l << 4));
        a1c = *(const uint4*)(stw + 1024 + (l << 4));
        bc  = LD_YT(0);
#pragma unroll
        for (int s = 0; s < 8; ++s) {
            LGKM0();                              // current pair's reads in regs
            char* ibuf = stw + ((s & 1) << 11);   // safe to overwrite now
            if (s < 6) {
                dma16(wp + W1B(mt0, s + 2) * 64 + l, ibuf);
                dma16(wp + W1B(mt1, s + 2) * 64 + l, ibuf + 1024);
            } else {                              // pairs 8,9 = L2 kc 0,1
                dma16(wp + W2B(mt0, s - 6) * 64 + l, ibuf);
                dma16(wp + W2B(mt1, s - 6) * 64 + l, ibuf + 1024);
            }
            VMCNT2();                             // pair s+1 landed
            char* rbuf = stw + (((s + 1) & 1) << 11);
            a0n = *(const uint4*)(rbuf + (l << 4));
            a1n = *(const uint4*)(rbuf + 1024 + (l << 4));
            if (s < 7) bn = LD_YT(s + 1);
            acc0 = MFMA(__builtin_bit_cast(short8, a0c), bc, acc0);
            acc1 = MFMA(__builtin_bit_cast(short8, a1c), bc, acc1);
            a0c = a0n; a1c = a1n; bc = bn;
        }
        store_h(smem, OFF_H, acc0, mt0, q, lm, sb);
        store_h(smem, OFF_H, acc1, mt1, q, lm, sb);
    }
    HBAR();

    // ---- Layer 2: H2 = tanh(W2t @ H + b2), steps s2=0..31 (pairs 8..39) ----
    {
        f32x16 acc0, acc1;
#pragma unroll
        for (int i = 0; i < 16; ++i) { acc0[i] = 0.f; acc1[i] = 0.f; }
        bc = LD_H(0);                             // waited at s2=0's LGKM0
#pragma unroll 4
        for (int s2 = 0; s2 < 32; ++s2) {
            LGKM0();
            char* ibuf = stw + ((s2 & 1) << 11);
            if (s2 < 30) {
                dma16(wp + W2B(mt0, s2 + 2) * 64 + l, ibuf);
                dma16(wp + W2B(mt1, s2 + 2) * 64 + l, ibuf + 1024);
            } else {                              // pairs 40,41 = L3 p0,p1
                const int j = 2 * (s2 - 30);
                dma16(wp + W3B(mt3, kc03 + j)     * 64 + l, ibuf);
                dma16(wp + W3B(mt3, kc03 + j + 1) * 64 + l, ibuf + 1024);
            }
            VMCNT2();
            char* rbuf = stw + (((s2 + 1) & 1) << 11);
            a0n = *(const uint4*)(rbuf + (l << 4));
            a1n = *(const uint4*)(rbuf + 1024 + (l << 4));
            if (s2 < 31) bn = LD_H(s2 + 1);
            acc0 = MFMA(__builtin_bit_cast(short8, a0c), bc, acc0);
            acc1 = MFMA(__builtin_bit_cast(short8, a1c), bc, acc1);
            a0c = a0n; a1c = a1n; bc = bn;
        }
        HBAR();                                   // all H reads done before overwrite
        store_h(smem, OFF_H, acc0, mt0, q, lm, sb + 512);
        store_h(smem, OFF_H, acc1, mt1, q, lm, sb + 512);
    }
    HBAR();

    // ---- Layer 3: Kt = W3t @ H2 + b3, split-K; steps s3=0..7 (pairs 40..47),
    //      2 kk tiles per step; pairs 46,47 issue NEXT EVAL's L1 pairs 0,1 ----
    {
        f32x16 acc;
#pragma unroll
        for (int i = 0; i < 16; ++i) acc[i] = 0.f;
        b0c = LD_H(kc03);
        b1c = LD_H(kc03 + 1);
#pragma unroll
        for (int s3 = 0; s3 < 8; ++s3) {
            LGKM0();
            char* ibuf = stw + ((s3 & 1) << 11);
            if (s3 < 6) {
                const int j = 2 * (s3 + 2);
                dma16(wp + W3B(mt3, kc03 + j)     * 64 + l, ibuf);
                dma16(wp + W3B(mt3, kc03 + j + 1) * 64 + l, ibuf + 1024);
            } else {                              // next eval L1 pairs 0,1
                const int kcn = s3 - 6;
                dma16(wp + W1B(mt0, kcn) * 64 + l, ibuf);
                dma16(wp + W1B(mt1, kcn) * 64 + l, ibuf + 1024);
            }
            VMCNT2();
            if (s3 < 7) {
                char* rbuf = stw + (((s3 + 1) & 1) << 11);
                a0n = *(const uint4*)(rbuf + (l << 4));
                a1n = *(const uint4*)(rbuf + 1024 + (l << 4));
                b0n = LD_H(kc03 + 2 * (s3 + 1));
                b1n = LD_H(kc03 + 2 * (s3 + 1) + 1);
            }
            acc = MFMA(__builtin_bit_cast(short8, a0c), b0c, acc);
            acc = MFMA(__builtin_bit_cast(short8, a1c), b1c, acc);
            a0c = a0n; a1c = a1n; b0c = b0n; b1c = b1n;
        }
        float* ko = (float*)(smem + koOff);
        if (w < 4) {
#pragma unroll
            for (int r = 0; r < 16; ++r) {
                const int row = (r & 3) + 8 * (r >> 2) + 4 * q;
                const int df  = mt3 * 32 + row;
                ko[lm * KO_S + df] = acc[r] + sb[1024 + df];
            }
        }
        HBAR();
        if (w >= 4) {
#pragma unroll
            for (int r = 0; r < 16; ++r) {
                const int row = (r & 3) + 8 * (r >> 2) + 4 * q;
                const int df  = mt3 * 32 + row;
                ko[lm * KO_S + df] += acc[r];
            }
        }
        HBAR();   // k buffer complete; safe for all threads to read
    }
}

__global__ __launch_bounds__(512, 1) void ode_kernel(
    const float* __restrict__ y0, const float* __restrict__ ts,
    const float* __restrict__ b1, const float* __restrict__ b2,
    const float* __restrict__ b3, const uint4* __restrict__ wp,
    float* __restrict__ yout)
{
    extern __shared__ __align__(16) char smem[];
    const int tid = threadIdx.x;
    const int g   = blockIdx.x;
    const int l   = tid & 63;
    const int w   = tid >> 6;

    // stage biases into LDS (visible after first HBAR inside mlp_eval)
    {
        float* sb = (float*)(smem + OFF_BIAS);
        for (int i = tid; i < 1152; i += 512) {
            float v = (i < 512) ? b1[i] : ((i < 1024) ? b2[i - 512] : b3[i - 1024]);
            sb[i] = v;
        }
    }

    // prime the DMA pipeline: L1 pairs 0,1 for this wave
    {
        char* stw = smem + OFF_ST + (w << 12);
        const int mt0 = 2 * w, mt1 = mt0 + 1;
        dma16(wp + W1B(mt0, 0) * 64 + l, stw);
        dma16(wp + W1B(mt1, 0) * 64 + l, stw + 1024);
        dma16(wp + W1B(mt0, 1) * 64 + l, stw + 2048);
        dma16(wp + W1B(mt1, 1) * 64 + l, stw + 2048 + 1024);
    }

    // load this thread's 8 y elements (row-major [B][128])
    const int row = g * 32 + (tid >> 4);
    const int c0  = (tid & 15) * 8;
    float y[8];
    {
        const float4* src = (const float4*)(y0 + row * 128 + c0);
        float4 v0 = src[0], v1 = src[1];
        y[0] = v0.x; y[1] = v0.y; y[2] = v0.z; y[3] = v0.w;
        y[4] = v1.x; y[5] = v1.y; y[6] = v1.z; y[7] = v1.w;
    }

    // scalar dt (wave-uniform; apply Butcher coefficients as literals)
    const float dt = __builtin_bit_cast(float, __builtin_amdgcn_readfirstlane(
        __builtin_bit_cast(int, (ts[1] - ts[0]) * (1.0f / (float)NSTEPS))));

    float yn[8], yt[8];

    for (int step = 0; step < NSTEPS; ++step) {

        write_ytmp(smem, tid, y);
        mlp_eval(smem, wp, tid, OFF_K0);                       // k1 -> K0
        {
            float k1[8];
            read_k(smem, OFF_K0, tid, k1);
#pragma unroll
            for (int i = 0; i < 8; ++i) {
                yn[i] = fmaf(dt, C_B1 * k1[i], y[i]);
                yt[i] = fmaf(dt, C_A21 * k1[i], y[i]);
            }
        }

        write_ytmp(smem, tid, yt);
        mlp_eval(smem, wp, tid, OFF_K0 + K_BYTES);             // k2 -> K1
        {
            float k1[8], k2[8];
            read_k(smem, OFF_K0, tid, k1);
            read_k(smem, OFF_K0 + K_BYTES, tid, k2);
#pragma unroll
            for (int i = 0; i < 8; ++i) {
                yn[i] = fmaf(dt, C_B2 * k2[i], yn[i]);
                yt[i] = fmaf(dt, fmaf(C_A32, k2[i], C_A31 * k1[i]), y[i]);
            }
        }

        write_ytmp(smem, tid, yt);
        mlp_eval(smem, wp, tid, OFF_K0 + 2 * K_BYTES);         // k3 -> K2
        {
            float k1[8], k2[8], k3[8];
            read_k(smem, OFF_K0, tid, k1);
            read_k(smem, OFF_K0 + K_BYTES, tid, k2);
            read_k(smem, OFF_K0 + 2 * K_BYTES, tid, k3);
#pragma unroll
            for (int i = 0; i < 8; ++i) {
                yn[i] = fmaf(dt, C_B3 * k3[i], yn[i]);
                yt[i] = fmaf(dt, fmaf(C_A43, k3[i],
                             fmaf(C_A42, k2[i], C_A41 * k1[i])), y[i]);
            }
        }

        write_ytmp(smem, tid, yt);
        mlp_eval(smem, wp, tid, OFF_K0 + 3 * K_BYTES);         // k4 -> K3
        {
            float k1[8], k2[8], k3[8], k4[8];
            read_k(smem, OFF_K0, tid, k1);
            read_k(smem, OFF_K0 + K_BYTES, tid, k2);
            read_k(smem, OFF_K0 + 2 * K_BYTES, tid, k3);
            read_k(smem, OFF_K0 + 3 * K_BYTES, tid, k4);
#pragma unroll
            for (int i = 0; i < 8; ++i) {
                yn[i] = fmaf(dt, C_B4 * k4[i], yn[i]);
                yt[i] = fmaf(dt, fmaf(C_A54, k4[i], fmaf(C_A53, k3[i],
                             fmaf(C_A52, k2[i], C_A51 * k1[i]))), y[i]);
            }
        }

        write_ytmp(smem, tid, yt);
        mlp_eval(smem, wp, tid, OFF_K0 + 4 * K_BYTES);         // k5 -> K4
        {
            float k1[8], k2[8], k3[8], k4[8], k5[8];
            read_k(smem, OFF_K0, tid, k1);
            read_k(smem, OFF_K0 + K_BYTES, tid, k2);
            read_k(smem, OFF_K0 + 2 * K_BYTES, tid, k3);
            read_k(smem, OFF_K0 + 3 * K_BYTES, tid, k4);
            read_k(smem, OFF_K0 + 4 * K_BYTES, tid, k5);
#pragma unroll
            for (int i = 0; i < 8; ++i) {
                yn[i] = fmaf(dt, C_B5 * k5[i], yn[i]);
                yt[i] = fmaf(dt, fmaf(C_A65, k5[i], fmaf(C_A64, k4[i],
                             fmaf(C_A63, k3[i], fmaf(C_A62, k2[i],
                             C_A61 * k1[i])))), y[i]);
            }
        }

        write_ytmp(smem, tid, yt);
        mlp_eval(smem, wp, tid, OFF_K0);                       // k6 -> K0 (k1 dead)
        {
            float k6[8];
            read_k(smem, OFF_K0, tid, k6);
#pragma unroll
            for (int i = 0; i < 8; ++i) {
                y[i] = fmaf(dt, C_B6 * k6[i], yn[i]);
            }
        }
    }

    // store final state (f32)
    {
        float4 o0, o1;
        o0.x = y[0]; o0.y = y[1]; o0.z = y[2]; o0.w = y[3];
        o1.x = y[4]; o1.y = y[5]; o1.z = y[6]; o1.w = y[7];
        float4* dst = (float4*)(yout + row * 128 + c0);
        dst[0] = o0; dst[1] = o1;
    }

    VMCNT0();   // drain dangling prefetch before endpgm
}

// ---------------------------------------------------------------------------
// Pack W1,W2,W3 (f32 row-major [K][M]) into bf16 A-fragment blocks for the
// transposed GEMMs: block (mt,kc) is 1 KB; lane l holds A[m=mt*32+(l&31)]
// [k=kc*16+8*(l>>5)+j], j=0..7, at block + l*16 + j*2.
// ---------------------------------------------------------------------------
__global__ void pack_weights(const float* __restrict__ W1, const float* __restrict__ W2,
                             const float* __restrict__ W3, unsigned short* __restrict__ out)
{
    const int tid = blockIdx.x * blockDim.x + threadIdx.x;   // 0..393215
    float v;
    if (tid < 65536) {                    // W1t [512 x 128], blocks: mt 0..15, kc 0..7
        const int e = tid, blk = e >> 9, wi = e & 511, l = wi >> 3, j = wi & 7;
        const int mt = blk >> 3, kc = blk & 7;
        const int m = mt * 32 + (l & 31);
        const int k = kc * 16 + 8 * (l >> 5) + j;
        v = W1[k * 512 + m];
    } else if (tid < 327680) {            // W2t [512 x 512], blocks: mt 0..15, kc 0..31
        const int e = tid - 65536, blk = e >> 9, wi = e & 511, l = wi >> 3, j = wi & 7;
        const int mt = blk >> 5, kc = blk & 31;
        const int m = mt * 32 + (l & 31);
        const int k = kc * 16 + 8 * (l >> 5) + j;
        v = W2[k * 512 + m];
    } else {                              // W3t [128 x 512], blocks: mt 0..3, kc 0..31
        const int e = tid - 327680, blk = e >> 9, wi = e & 511, l = wi >> 3, j = wi & 7;
        const int mt = blk >> 5, kc = blk & 31;
        const int m = mt * 32 + (l & 31);
        const int k = kc * 16 + 8 * (l >> 5) + j;
        v = W3[k * 128 + m];
    }
    out[tid] = __builtin_bit_cast(unsigned short, __float2bfloat16(v));
}

extern "C" void kernel_launch(void* const* d_in, const int* in_sizes, int n_in,
                              void* d_out, int out_size, void* d_ws, size_t ws_size,
                              hipStream_t stream)
{
    const float* y0 = (const float*)d_in[0];
    const float* ts = (const float*)d_in[1];
    const float* W1 = (const float*)d_in[2];
    const float* b1 = (const float*)d_in[3];
    const float* W2 = (const float*)d_in[4];
    const float* b2 = (const float*)d_in[5];
    const float* W3 = (const float*)d_in[6];
    const float* b3 = (const float*)d_in[7];
    unsigned short* wp = (unsigned short*)d_ws;   // 786432 B of packed bf16 weights

    pack_weights<<<1536, 256, 0, stream>>>(W1, W2, W3, wp);

    (void)hipFuncSetAttribute((const void*)ode_kernel,
                              hipFuncAttributeMaxDynamicSharedMemorySize, SMEM_BYTES);
    ode_kernel<<<256, 512, SMEM_BYTES, stream>>>(y0, ts, b1, b2, b3,
                                                 (const uint4*)wp, (float*)d_out);
}